// Round 3
// baseline (347.571 us; speedup 1.0000x reference)
//
#include <hip/hip_runtime.h>

// ProjectionPursuitProbe: h' = scale * (h - P G^{-1} P^T h), G = P^T P
// B=8, S=4096, F=1024, R=64. Rows N = 32768.
//
// v4: contiguous-access experiment + prep fusion.
//  - All global accesses in pp_main are contiguous 1KB-per-wave-instruction:
//    * phase-1 H staging: 8 rows x 128B full lines per instr (was 16 rows x half-lines)
//    * B operands (Ptf/Pbf/Wf) pre-swizzled into lane-ordered fragment streams
//    * phase-3 H re-read / out store: f32x4 per lane, 8 rows x 128B per instr,
//      via a wave-private LDS transpose tile aliased onto Ha (no extra LDS)
//  - pp_prep: gram + pack + invert fused in one kernel (16 blocks, device-scope
//    counter; block 0 inverts after all partials land). 3 launches -> 2.

typedef __attribute__((ext_vector_type(8))) short bf16x8;
typedef __attribute__((ext_vector_type(4))) float f32x4;

#define MFMA_B16(a, b, c) __builtin_amdgcn_mfma_f32_16x16x32_bf16((a), (b), (c), 0, 0, 0)

__device__ __forceinline__ unsigned short bf16bits(float x) {
  union { float f; unsigned u; } v; v.f = x;
  return (unsigned short)((v.u + 0x7fffu + ((v.u >> 16) & 1u)) >> 16);  // RNE
}

// ---------------- K1: prep = gram partials + fragment-stream packing + invert -------------
// Frag streams: every entry is (frag_idx*64 + lane)*8 bf16, so a wave load of frag f is a
// single fully-contiguous 1KB instruction.
//  Ptf (phase1 B): frag (ch,it,t) idx=(ch*4+it)*4+t ; elem e = P[ch*128+it*32+quad*8+e][t*16+c16]
//  Pbf (phase3 B): frag (g,t2,j)  idx=g*8+t2*2+j    ; elem e = P[g*64+t2*16+c16][j*32+quad*8+e]
//  Wf  (phase2 B): frag (kk,t)    idx=kk*4+t        ; elem e = W[kk*32+quad*8+e][t*16+c16]
__global__ void pp_prep(const float* __restrict__ P, float* __restrict__ partial,
                        unsigned short* __restrict__ Ptf, unsigned short* __restrict__ Pbf,
                        unsigned short* __restrict__ Wf, unsigned int* __restrict__ done) {
  __shared__ float Pl[64][68];
  __shared__ float A[64][68];
  const int tid = threadIdx.x, b = blockIdx.x;
  // stage 64 f-rows of P (64x64 fp32)
  #pragma unroll
  for (int u = 0; u < 4; ++u) {
    const int f = tid >> 2, r = (tid & 3) * 16 + 4 * u;
    *(f32x4*)&Pl[f][r] = *(const f32x4*)(P + (size_t)(b * 64 + f) * 64 + r);
  }
  __syncthreads();

  // ---- Ptf slice: this block covers f in [64b, 64b+64) -> ch=b>>1, it in {2(b&1), 2(b&1)+1}
  #pragma unroll
  for (int u = 0; u < 2; ++u) {
    const int flat = tid + 256 * u;          // 8 frags x 64 lanes
    const int lf = flat >> 6, lane = flat & 63;
    const int c16 = lane & 15, quad = lane >> 4;
    const int it_loc = lf >> 2, t = lf & 3;
    const int flb = it_loc * 32 + quad * 8;  // local f base
    bf16x8 w;
    #pragma unroll
    for (int e = 0; e < 8; ++e) w[e] = (short)bf16bits(Pl[flb + e][t * 16 + c16]);
    const int gidx = ((b >> 1) * 4 + 2 * (b & 1) + it_loc) * 4 + t;
    *(bf16x8*)(Ptf + ((size_t)gidx * 64 + lane) * 8) = w;
  }
  // ---- Pbf slice: g = b
  #pragma unroll
  for (int u = 0; u < 2; ++u) {
    const int flat = tid + 256 * u;
    const int lf = flat >> 6, lane = flat & 63;
    const int c16 = lane & 15, quad = lane >> 4;
    const int t2 = lf >> 1, j = lf & 1;
    f32x4 p0 = *(const f32x4*)&Pl[t2 * 16 + c16][j * 32 + quad * 8];
    f32x4 p1 = *(const f32x4*)&Pl[t2 * 16 + c16][j * 32 + quad * 8 + 4];
    bf16x8 w;
    #pragma unroll
    for (int e = 0; e < 4; ++e) { w[e] = (short)bf16bits(p0[e]); w[4 + e] = (short)bf16bits(p1[e]); }
    const int gidx = b * 8 + t2 * 2 + j;
    *(bf16x8*)(Pbf + ((size_t)gidx * 64 + lane) * 8) = w;
  }

  // ---- gram partial: partial[b] = Pchunk^T @ Pchunk
  {
    const int a0 = (tid >> 4) * 4, b0 = (tid & 15) * 4;
    f32x4 acc[4];
    #pragma unroll
    for (int i = 0; i < 4; ++i) acc[i] = (f32x4){0.f, 0.f, 0.f, 0.f};
    for (int k = 0; k < 64; ++k) {
      f32x4 av = *(const f32x4*)&Pl[k][a0];
      f32x4 bv = *(const f32x4*)&Pl[k][b0];
      #pragma unroll
      for (int i = 0; i < 4; ++i) acc[i] += av[i] * bv;
    }
    #pragma unroll
    for (int i = 0; i < 4; ++i)
      *(f32x4*)(partial + (size_t)b * 4096 + (size_t)(a0 + i) * 64 + b0) = acc[i];
  }
  __threadfence();
  __syncthreads();
  if (tid == 0) atomicAdd(done, 1u);
  if (b != 0) return;

  // ---- block 0: wait for all partials, then 4-wave Gauss-Jordan invert ----
  if (tid == 0) {
    while (__hip_atomic_load(done, __ATOMIC_ACQUIRE, __HIP_MEMORY_SCOPE_AGENT) < 16u)
      __builtin_amdgcn_s_sleep(8);
  }
  __syncthreads();
  __threadfence();
  const int i = tid >> 2, q16 = (tid & 3) * 16;
  #pragma unroll
  for (int u = 0; u < 4; ++u) {
    f32x4 s = (f32x4){0.f, 0.f, 0.f, 0.f};
    const int off = i * 64 + q16 + 4 * u;
    for (int p = 0; p < 16; ++p) s += *(const f32x4*)(partial + (size_t)p * 4096 + off);
    *(f32x4*)&A[i][q16 + 4 * u] = s;
  }
  __syncthreads();
  for (int k = 0; k < 64; ++k) {
    const float d = 1.0f / A[k][k];
    const float f = A[i][k];
    f32x4 prs[4], cur[4];
    #pragma unroll
    for (int u = 0; u < 4; ++u) {
      prs[u] = *(const f32x4*)&A[k][q16 + 4 * u];
      cur[u] = *(const f32x4*)&A[i][q16 + 4 * u];
    }
    __syncthreads();  // all reads done before any writes
    const int kl = k - q16;
    #pragma unroll
    for (int u = 0; u < 4; ++u) {
      f32x4 pv = prs[u] * d;
      if (kl >= u * 4 && kl < u * 4 + 4) { pv[kl - u * 4] = d; cur[u][kl - u * 4] = 0.f; }
      f32x4 res = (i == k) ? pv : (cur[u] - f * pv);
      *(f32x4*)&A[i][q16 + 4 * u] = res;
    }
    __syncthreads();
  }
  // ---- Wf emit (lane-ordered fragment stream)
  #pragma unroll
  for (int u = 0; u < 2; ++u) {
    const int flat = tid + 256 * u;
    const int lf = flat >> 6, lane = flat & 63;
    const int c16 = lane & 15, quad = lane >> 4;
    const int kk = lf >> 2, tf = lf & 3;
    bf16x8 w;
    #pragma unroll
    for (int e = 0; e < 8; ++e) w[e] = (short)bf16bits(A[kk * 32 + quad * 8 + e][tf * 16 + c16]);
    *(bf16x8*)(Wf + ((size_t)(kk * 4 + tf) * 64 + lane) * 8) = w;
  }
}

// ---------------- K2: fused main kernel, 64 rows/block, contiguous access ----------------
__global__ __launch_bounds__(256, 2) void pp_main(
    const float* __restrict__ H, const unsigned short* __restrict__ Ptf,
    const unsigned short* __restrict__ Pbf, const unsigned short* __restrict__ Wf,
    float* __restrict__ out) {
  __shared__ __align__(16) unsigned short Ha[64][136];  // bf16 H chunk; phase3: aliased f32 Tl
  __shared__ __align__(16) unsigned short Yl[64][72];   // Y bf16
  __shared__ __align__(16) unsigned short Cl[64][72];   // C bf16
  __shared__ float rowsqL[64];
  __shared__ float scalevL[64];

  const int tid = threadIdx.x;
  const int lane = tid & 63, wid = tid >> 6;
  const int c16 = lane & 15, quad = lane >> 4;
  const int strip = wid * 16;
  const long row0 = (long)blockIdx.x * 64;
  // staging coords: 8 threads/row, 16B per thread per pass -> 8 rows x 128B per instr
  const int sr = tid >> 3;       // 0..31 (rows sr and sr+32)
  const int sc8 = (tid & 7) * 4; // float offset within 128-col chunk

  f32x4 accY[4];
  #pragma unroll
  for (int t = 0; t < 4; ++t) accY[t] = (f32x4){0.f, 0.f, 0.f, 0.f};
  float sqa0 = 0.f, sqa1 = 0.f;

  // ---- phase 1: Y = H @ P (K=1024, 8 chunks of 128), full-line staged ----
  for (int ch = 0; ch < 8; ++ch) {
    #pragma unroll
    for (int ph = 0; ph < 2; ++ph) {
      const int row = ph * 32 + sr;
      const float* hp = H + (row0 + row) * 1024 + ch * 128;
      #pragma unroll
      for (int p = 0; p < 4; ++p) {
        const int col = p * 32 + sc8;
        f32x4 v = *(const f32x4*)(hp + col);
        const float d2 = v[0] * v[0] + v[1] * v[1] + v[2] * v[2] + v[3] * v[3];
        if (ph == 0) sqa0 += d2; else sqa1 += d2;
        unsigned lo = (unsigned)bf16bits(v[0]) | ((unsigned)bf16bits(v[1]) << 16);
        unsigned hi = (unsigned)bf16bits(v[2]) | ((unsigned)bf16bits(v[3]) << 16);
        *(unsigned long long*)&Ha[row][col] =
            (unsigned long long)lo | ((unsigned long long)hi << 32);
      }
    }
    __syncthreads();
    #pragma unroll
    for (int it = 0; it < 4; ++it) {
      bf16x8 a = *(const bf16x8*)&Ha[strip + c16][it * 32 + quad * 8];
      #pragma unroll
      for (int t = 0; t < 4; ++t) {
        bf16x8 b = *(const bf16x8*)(Ptf + (((size_t)(ch * 4 + it) * 4 + t) * 64 + lane) * 8);
        accY[t] = MFMA_B16(a, b, accY[t]);
      }
    }
    __syncthreads();
  }

  // row sum-of-squares: 8 threads per row, reduce within wave
  sqa0 += __shfl_xor(sqa0, 1); sqa1 += __shfl_xor(sqa1, 1);
  sqa0 += __shfl_xor(sqa0, 2); sqa1 += __shfl_xor(sqa1, 2);
  sqa0 += __shfl_xor(sqa0, 4); sqa1 += __shfl_xor(sqa1, 4);
  if ((lane & 7) == 0) { rowsqL[sr] = sqa0; rowsqL[sr + 32] = sqa1; }

  // Y -> LDS bf16 (wave-private rows)
  #pragma unroll
  for (int t = 0; t < 4; ++t)
    #pragma unroll
    for (int r = 0; r < 4; ++r)  // D layout: col = lane&15, row = quad*4+reg
      Yl[strip + quad * 4 + r][t * 16 + c16] = bf16bits(accY[t][r]);
  __syncthreads();  // rowsqL is cross-wave

  // ---- phase 2: C = Y @ W (Wf fragment stream from global, L2-hot) ----
  f32x4 accC[4];
  #pragma unroll
  for (int t = 0; t < 4; ++t) accC[t] = (f32x4){0.f, 0.f, 0.f, 0.f};
  #pragma unroll
  for (int kk = 0; kk < 2; ++kk) {
    bf16x8 a = *(const bf16x8*)&Yl[strip + c16][kk * 32 + quad * 8];
    #pragma unroll
    for (int t = 0; t < 4; ++t) {
      bf16x8 b = *(const bf16x8*)(Wf + (((size_t)kk * 4 + t) * 64 + lane) * 8);
      accC[t] = MFMA_B16(a, b, accC[t]);
    }
  }
  #pragma unroll
  for (int t = 0; t < 4; ++t)
    #pragma unroll
    for (int r = 0; r < 4; ++r)
      Cl[strip + quad * 4 + r][t * 16 + c16] = bf16bits(accC[t][r]);

  // ---- per-row dot = y.c, scale = sqrt(o2/(o2-dot)) ----
  #pragma unroll
  for (int r = 0; r < 4; ++r) {
    float dd = accY[0][r] * accC[0][r] + accY[1][r] * accC[1][r] +
               accY[2][r] * accC[2][r] + accY[3][r] * accC[3][r];
    dd += __shfl_xor(dd, 1);
    dd += __shfl_xor(dd, 2);
    dd += __shfl_xor(dd, 4);
    dd += __shfl_xor(dd, 8);
    if (c16 == 0) {
      const int rowm = strip + quad * 4 + r;
      const float o2 = rowsqL[rowm];
      const float n2 = fmaxf(o2 - dd, 1e-30f);
      scalevL[rowm] = sqrtf(o2 / n2);
    }
  }

  // ---- phase 3: out = (H - C @ P^T) * scale, via wave-private LDS tile ----
  bf16x8 ca0 = *(const bf16x8*)&Cl[strip + c16][quad * 8];       // A[m][k=r], k in [0,32)
  bf16x8 ca1 = *(const bf16x8*)&Cl[strip + c16][32 + quad * 8];  // k in [32,64)
  float* Tl = (float*)(&Ha[0][0]) + wid * 1088;  // 16 x 68 f32, wave-private (Ha aliased)
  const int pr = lane >> 3;        // 0..7 row within 8-row group
  const int pc = (lane & 7) * 4;   // float col within 32-col group
  const float scA = scalevL[strip + pr];       // rows strip+pr     (written by this wave)
  const float scB = scalevL[strip + 8 + pr];   // rows strip+8+pr
  const long growA = row0 + strip + pr;
  const long growB = growA + 8;
  const bool fsA = ((growA & 4095) == 0);      // s==0 passthrough (only possible on growA)

  for (int g = 0; g < 16; ++g) {
    bf16x8 bb[8];
    #pragma unroll
    for (int f8 = 0; f8 < 8; ++f8)
      bb[f8] = *(const bf16x8*)(Pbf + (((size_t)g * 8 + f8) * 64 + lane) * 8);
    #pragma unroll
    for (int t2 = 0; t2 < 4; ++t2) {
      f32x4 acc = (f32x4){0.f, 0.f, 0.f, 0.f};
      acc = MFMA_B16(ca0, bb[t2 * 2], acc);
      acc = MFMA_B16(ca1, bb[t2 * 2 + 1], acc);
      #pragma unroll
      for (int r = 0; r < 4; ++r)
        Tl[(quad * 4 + r) * 68 + t2 * 16 + c16] = acc[r];
    }
    __builtin_amdgcn_wave_barrier();  // keep Tl writes before reads (sched fence)
    #pragma unroll
    for (int s = 0; s < 4; ++s) {
      const int trow = (s & 1) * 8 + pr;
      const int fcol = (s >> 1) * 32 + pc;
      f32x4 tv = *(const f32x4*)&Tl[trow * 68 + fcol];
      const long grow = (s & 1) ? growB : growA;
      const float scv = (s & 1) ? scB : scA;
      const long base = grow * 1024 + g * 64 + fcol;
      f32x4 h = *(const f32x4*)(H + base);  // L2/L3 hit, full-line contiguous
      f32x4 o;
      #pragma unroll
      for (int e = 0; e < 4; ++e) o[e] = (h[e] - tv[e]) * scv;
      if ((s & 1) == 0 && fsA) o = h;       // exact copy for s==0 rows
      *(f32x4*)(out + base) = o;
    }
    __builtin_amdgcn_wave_barrier();  // keep this g's reads before next g's writes
  }
}

extern "C" void kernel_launch(void* const* d_in, const int* in_sizes, int n_in,
                              void* d_out, int out_size, void* d_ws, size_t ws_size,
                              hipStream_t stream) {
  const float* H = (const float*)d_in[0];   // 8*4096*1024 fp32
  const float* P = (const float*)d_in[1];   // 1024*64 fp32
  float* out = (float*)d_out;
  // ws: partial (16*4096 f32) | Ptf (65536 bf16) | Pbf (65536 bf16) | Wf (4096 bf16) | done
  float* partial = (float*)d_ws;
  unsigned short* Ptf = (unsigned short*)(partial + 16 * 4096);
  unsigned short* Pbf = Ptf + 65536;
  unsigned short* Wf = Pbf + 65536;
  unsigned int* done = (unsigned int*)(Wf + 4096);

  hipMemsetAsync(done, 0, sizeof(unsigned int), stream);
  pp_prep<<<16, 256, 0, stream>>>(P, partial, Ptf, Pbf, Wf, done);
  pp_main<<<512, 256, 0, stream>>>(H, Ptf, Pbf, Wf, out);
}

// Round 4
// 329.501 us; speedup vs baseline: 1.0548x; 1.0548x over previous
//
#include <hip/hip_runtime.h>

// ProjectionPursuitProbe: h' = scale * (h - P G^{-1} P^T h), G = P^T P
// B=8, S=4096, F=1024, R=64. Rows N = 32768.
//
// v5: split the fused main kernel into two pure streaming kernels.
//  - pp_y: Y = H@P (register-direct, frag-stream B), C = Y@W, per-row scale.
//    Zero barriers, zero cross-wave LDS. Writes Cf (bf16 frags, 4MB) + Sc (f32).
//  - pp_apply: out = (H - C@P^T)*scale with SWAPPED MFMA operands (A=P-frag,
//    B=C-frag) so D is f-major: one f32x4 H-load + one f32x4 store per lane per
//    tile (v0 used 4+4 scalars). SW-pipelined depth-4 (H) / depth-2 (P-frags).
//    Zero barriers, zero LDS, no transpose tile.
//  - prep kernels (gram+pack, invert+Wf) carried from v4 (verified).

typedef __attribute__((ext_vector_type(8))) short bf16x8;
typedef __attribute__((ext_vector_type(4))) float f32x4;

#define MFMA_B16(a, b, c) __builtin_amdgcn_mfma_f32_16x16x32_bf16((a), (b), (c), 0, 0, 0)

__device__ __forceinline__ unsigned short bf16bits(float x) {
  union { float f; unsigned u; } v; v.f = x;
  return (unsigned short)((v.u + 0x7fffu + ((v.u >> 16) & 1u)) >> 16);  // RNE
}

// ---------------- K1: gram partials + fragment-stream packing (Ptf, Pbf) ------------------
//  Ptf (pp_y B):    frag (ch,it,t) idx=(ch*4+it)*4+t ; elem e = P[ch*128+it*32+quad*8+e][t*16+c16]
//  Pbf (apply A):   frag idx=2*ft+j (ft=16-f tile)   ; elem e = P[ft*16+c16][j*32+quad*8+e]
__global__ void pp_gram(const float* __restrict__ P, float* __restrict__ partial,
                        unsigned short* __restrict__ Ptf, unsigned short* __restrict__ Pbf) {
  __shared__ float Pl[64][68];
  const int tid = threadIdx.x, b = blockIdx.x;
  #pragma unroll
  for (int u = 0; u < 4; ++u) {
    const int f = tid >> 2, r = (tid & 3) * 16 + 4 * u;
    *(f32x4*)&Pl[f][r] = *(const f32x4*)(P + (size_t)(b * 64 + f) * 64 + r);
  }
  __syncthreads();

  // Ptf slice: this block covers f in [64b, 64b+64) -> ch=b>>1, it in {2(b&1), 2(b&1)+1}
  #pragma unroll
  for (int u = 0; u < 2; ++u) {
    const int flat = tid + 256 * u;          // 8 frags x 64 lanes
    const int lf = flat >> 6, lane = flat & 63;
    const int c16 = lane & 15, quad = lane >> 4;
    const int it_loc = lf >> 2, t = lf & 3;
    const int flb = it_loc * 32 + quad * 8;  // local f base
    bf16x8 w;
    #pragma unroll
    for (int e = 0; e < 8; ++e) w[e] = (short)bf16bits(Pl[flb + e][t * 16 + c16]);
    const int gidx = ((b >> 1) * 4 + 2 * (b & 1) + it_loc) * 4 + t;
    *(bf16x8*)(Ptf + ((size_t)gidx * 64 + lane) * 8) = w;
  }
  // Pbf slice: ft tiles 4b..4b+3 (local t2=0..3), frag idx = 2*ft+j
  #pragma unroll
  for (int u = 0; u < 2; ++u) {
    const int flat = tid + 256 * u;
    const int lf = flat >> 6, lane = flat & 63;
    const int c16 = lane & 15, quad = lane >> 4;
    const int t2 = lf >> 1, j = lf & 1;
    f32x4 p0 = *(const f32x4*)&Pl[t2 * 16 + c16][j * 32 + quad * 8];
    f32x4 p1 = *(const f32x4*)&Pl[t2 * 16 + c16][j * 32 + quad * 8 + 4];
    bf16x8 w;
    #pragma unroll
    for (int e = 0; e < 4; ++e) { w[e] = (short)bf16bits(p0[e]); w[4 + e] = (short)bf16bits(p1[e]); }
    const int gidx = 2 * (b * 4 + t2) + j;
    *(bf16x8*)(Pbf + ((size_t)gidx * 64 + lane) * 8) = w;
  }

  // gram partial: partial[b] = Pchunk^T @ Pchunk
  const int a0 = (tid >> 4) * 4, b0 = (tid & 15) * 4;
  f32x4 acc[4];
  #pragma unroll
  for (int i = 0; i < 4; ++i) acc[i] = (f32x4){0.f, 0.f, 0.f, 0.f};
  for (int k = 0; k < 64; ++k) {
    f32x4 av = *(const f32x4*)&Pl[k][a0];
    f32x4 bv = *(const f32x4*)&Pl[k][b0];
    #pragma unroll
    for (int i = 0; i < 4; ++i) acc[i] += av[i] * bv;
  }
  #pragma unroll
  for (int i = 0; i < 4; ++i)
    *(f32x4*)(partial + (size_t)b * 4096 + (size_t)(a0 + i) * 64 + b0) = acc[i];
}

// ---------------- K2: G = sum partials; W = G^{-1} (4-wave GJ); emit Wf frag stream -------
//  Wf (pp_y phase-2 B): frag (kk,t) idx=kk*4+t ; elem e = W[kk*32+quad*8+e][t*16+c16]
__global__ void pp_invert(const float* __restrict__ partial, unsigned short* __restrict__ Wf) {
  __shared__ float A[64][68];
  const int tid = threadIdx.x;
  const int i = tid >> 2, q16 = (tid & 3) * 16;
  #pragma unroll
  for (int u = 0; u < 4; ++u) {
    f32x4 s = (f32x4){0.f, 0.f, 0.f, 0.f};
    const int off = i * 64 + q16 + 4 * u;
    for (int p = 0; p < 16; ++p) s += *(const f32x4*)(partial + (size_t)p * 4096 + off);
    *(f32x4*)&A[i][q16 + 4 * u] = s;
  }
  __syncthreads();
  for (int k = 0; k < 64; ++k) {
    const float d = 1.0f / A[k][k];
    const float f = A[i][k];
    f32x4 prs[4], cur[4];
    #pragma unroll
    for (int u = 0; u < 4; ++u) {
      prs[u] = *(const f32x4*)&A[k][q16 + 4 * u];
      cur[u] = *(const f32x4*)&A[i][q16 + 4 * u];
    }
    __syncthreads();  // all reads done before any writes
    const int kl = k - q16;
    #pragma unroll
    for (int u = 0; u < 4; ++u) {
      f32x4 pv = prs[u] * d;
      if (kl >= u * 4 && kl < u * 4 + 4) { pv[kl - u * 4] = d; cur[u][kl - u * 4] = 0.f; }
      f32x4 res = (i == k) ? pv : (cur[u] - f * pv);
      *(f32x4*)&A[i][q16 + 4 * u] = res;
    }
    __syncthreads();
  }
  #pragma unroll
  for (int u = 0; u < 2; ++u) {
    const int flat = tid + 256 * u;
    const int lf = flat >> 6, lane = flat & 63;
    const int c16 = lane & 15, quad = lane >> 4;
    const int kk = lf >> 2, tf = lf & 3;
    bf16x8 w;
    #pragma unroll
    for (int e = 0; e < 8; ++e) w[e] = (short)bf16bits(A[kk * 32 + quad * 8 + e][tf * 16 + c16]);
    *(bf16x8*)(Wf + ((size_t)(kk * 4 + tf) * 64 + lane) * 8) = w;
  }
}

// ---------------- K3: pp_y — Y = H@P, C = Y@W, scale. Zero barriers. ----------------------
__device__ __forceinline__ void ld_chunk(const float* __restrict__ hp, int ch, f32x4* v) {
  #pragma unroll
  for (int it = 0; it < 4; ++it) {
    v[2 * it] = *(const f32x4*)(hp + ch * 128 + it * 32);
    v[2 * it + 1] = *(const f32x4*)(hp + ch * 128 + it * 32 + 4);
  }
}

__device__ __forceinline__ void comp_chunk(const f32x4* v, const unsigned short* __restrict__ bp0,
                                           int ch, f32x4* accY, float& sqacc) {
  #pragma unroll
  for (int it = 0; it < 4; ++it) {
    const f32x4 v0 = v[2 * it], v1 = v[2 * it + 1];
    sqacc += v0[0] * v0[0] + v0[1] * v0[1] + v0[2] * v0[2] + v0[3] * v0[3] +
             v1[0] * v1[0] + v1[1] * v1[1] + v1[2] * v1[2] + v1[3] * v1[3];
    bf16x8 a;
    a[0] = (short)bf16bits(v0[0]); a[1] = (short)bf16bits(v0[1]);
    a[2] = (short)bf16bits(v0[2]); a[3] = (short)bf16bits(v0[3]);
    a[4] = (short)bf16bits(v1[0]); a[5] = (short)bf16bits(v1[1]);
    a[6] = (short)bf16bits(v1[2]); a[7] = (short)bf16bits(v1[3]);
    #pragma unroll
    for (int t = 0; t < 4; ++t) {  // B[k=f][n=r], k-contiguous frag stream
      bf16x8 b = *(const bf16x8*)(bp0 + (size_t)((ch * 4 + it) * 4 + t) * 512);
      accY[t] = MFMA_B16(a, b, accY[t]);
    }
  }
}

__global__ __launch_bounds__(256, 2) void pp_y(
    const float* __restrict__ H, const unsigned short* __restrict__ Ptf,
    const unsigned short* __restrict__ Wf, unsigned short* __restrict__ Cf,
    float* __restrict__ Sc) {
  __shared__ __align__(16) unsigned short Yt[4][16][72];  // wave-private
  __shared__ __align__(16) unsigned short Ct[4][16][72];  // wave-private

  const int tid = threadIdx.x;
  const int lane = tid & 63, wid = tid >> 6;
  const int c16 = lane & 15, quad = lane >> 4;
  const int strip = wid * 16;
  const long row0 = (long)blockIdx.x * 64;

  f32x4 accY[4];
  #pragma unroll
  for (int t = 0; t < 4; ++t) accY[t] = (f32x4){0.f, 0.f, 0.f, 0.f};
  float sqacc = 0.f;
  const float* hp = H + (row0 + strip + c16) * 1024 + quad * 8;
  const unsigned short* bp0 = Ptf + lane * 8;

  {  // depth-2 software pipeline over 8 K-chunks of 128
    f32x4 va[8], vb[8];
    ld_chunk(hp, 0, va);
    ld_chunk(hp, 1, vb);
    comp_chunk(va, bp0, 0, accY, sqacc); ld_chunk(hp, 2, va);
    comp_chunk(vb, bp0, 1, accY, sqacc); ld_chunk(hp, 3, vb);
    comp_chunk(va, bp0, 2, accY, sqacc); ld_chunk(hp, 4, va);
    comp_chunk(vb, bp0, 3, accY, sqacc); ld_chunk(hp, 5, vb);
    comp_chunk(va, bp0, 4, accY, sqacc); ld_chunk(hp, 6, va);
    comp_chunk(vb, bp0, 5, accY, sqacc); ld_chunk(hp, 7, vb);
    comp_chunk(va, bp0, 6, accY, sqacc);
    comp_chunk(vb, bp0, 7, accY, sqacc);
  }

  // row sum-of-squares: lane holds partial for row strip+c16; reduce across quads
  sqacc += __shfl_xor(sqacc, 16);
  sqacc += __shfl_xor(sqacc, 32);

  // Y -> wave-private LDS (bf16); intra-wave RAW ordered by compiler lgkmcnt
  #pragma unroll
  for (int t = 0; t < 4; ++t)
    #pragma unroll
    for (int r = 0; r < 4; ++r)  // D layout: col = lane&15, row = quad*4+reg
      Yt[wid][quad * 4 + r][t * 16 + c16] = bf16bits(accY[t][r]);

  // phase 2: C = Y @ W (Wf frag stream, L2-hot)
  f32x4 accC[4];
  #pragma unroll
  for (int t = 0; t < 4; ++t) accC[t] = (f32x4){0.f, 0.f, 0.f, 0.f};
  #pragma unroll
  for (int kk = 0; kk < 2; ++kk) {
    bf16x8 a = *(const bf16x8*)&Yt[wid][c16][kk * 32 + quad * 8];
    #pragma unroll
    for (int t = 0; t < 4; ++t) {
      bf16x8 b = *(const bf16x8*)(Wf + ((size_t)(kk * 4 + t) * 64 + lane) * 8);
      accC[t] = MFMA_B16(a, b, accC[t]);
    }
  }
  #pragma unroll
  for (int t = 0; t < 4; ++t)
    #pragma unroll
    for (int r = 0; r < 4; ++r)
      Ct[wid][quad * 4 + r][t * 16 + c16] = bf16bits(accC[t][r]);

  // per-row dot = y.c, scale = sqrt(o2/(o2-dot))
  #pragma unroll
  for (int r = 0; r < 4; ++r) {
    float dd = accY[0][r] * accC[0][r] + accY[1][r] * accC[1][r] +
               accY[2][r] * accC[2][r] + accY[3][r] * accC[3][r];
    dd += __shfl_xor(dd, 1);
    dd += __shfl_xor(dd, 2);
    dd += __shfl_xor(dd, 4);
    dd += __shfl_xor(dd, 8);
    const float o2 = __shfl(sqacc, quad * 4 + r);
    if (c16 == 0) {
      const float n2 = fmaxf(o2 - dd, 1e-30f);
      Sc[row0 + strip + quad * 4 + r] = sqrtf(o2 / n2);
    }
  }

  // emit C in pp_apply's B-fragment layout: frag j elem e = C[strip+c16][j*32+quad*8+e]
  bf16x8 cb0 = *(const bf16x8*)&Ct[wid][c16][quad * 8];
  bf16x8 cb1 = *(const bf16x8*)&Ct[wid][c16][32 + quad * 8];
  const size_t s = (size_t)(row0 + strip) >> 4;  // global 16-row strip id
  *(bf16x8*)(Cf + (s * 2 + 0) * 512 + lane * 8) = cb0;
  *(bf16x8*)(Cf + (s * 2 + 1) * 512 + lane * 8) = cb1;
}

// ---------------- K4: pp_apply — out = (H - C@P^T)*scale. Zero barriers, zero LDS. --------
// Swapped operands: A = Pbf frag (A[f][r]), B = Cf frag (B[r][m]) -> D[f][m]:
// lane (c16,quad) reg r: D row f = ft*16 + quad*4 + r (4 consecutive f), col m = c16.
__global__ __launch_bounds__(256, 2) void pp_apply(
    const float* __restrict__ H, const unsigned short* __restrict__ Pbf,
    const unsigned short* __restrict__ Cf, const float* __restrict__ Sc,
    float* __restrict__ out) {
  const int tid = threadIdx.x;
  const int lane = tid & 63, wid = tid >> 6;
  const int c16 = lane & 15, quad = lane >> 4;
  const int strip = wid * 16;
  const long row0 = (long)blockIdx.x * 64;

  const size_t s = (size_t)(row0 + strip) >> 4;
  const bf16x8 cb0 = *(const bf16x8*)(Cf + (s * 2 + 0) * 512 + lane * 8);
  const bf16x8 cb1 = *(const bf16x8*)(Cf + (s * 2 + 1) * 512 + lane * 8);

  const long grow = row0 + strip + c16;       // this lane's output row
  const float sc = Sc[grow];
  const bool fs = ((grow & 4095) == 0);       // s==0 rows pass through exactly
  const float* hp = H + grow * 1024 + quad * 4;
  float* op = out + grow * 1024 + quad * 4;
  const unsigned short* pb = Pbf + lane * 8;  // frag idx 2*ft+j, stride 512 shorts

  f32x4 hbuf[4];
  bf16x8 abuf[2][2];
  #pragma unroll
  for (int i = 0; i < 4; ++i) hbuf[i] = *(const f32x4*)(hp + (size_t)i * 16);
  #pragma unroll
  for (int i = 0; i < 2; ++i) {
    abuf[i][0] = *(const bf16x8*)(pb + (size_t)(2 * i + 0) * 512);
    abuf[i][1] = *(const bf16x8*)(pb + (size_t)(2 * i + 1) * 512);
  }

  #pragma unroll 4
  for (int ft = 0; ft < 64; ++ft) {
    const f32x4 hcur = hbuf[ft & 3];
    const bf16x8 pa0 = abuf[ft & 1][0];
    const bf16x8 pa1 = abuf[ft & 1][1];
    if (ft + 4 < 64) hbuf[ft & 3] = *(const f32x4*)(hp + (size_t)(ft + 4) * 16);
    if (ft + 2 < 64) {
      abuf[ft & 1][0] = *(const bf16x8*)(pb + (size_t)(2 * (ft + 2) + 0) * 512);
      abuf[ft & 1][1] = *(const bf16x8*)(pb + (size_t)(2 * (ft + 2) + 1) * 512);
    }
    f32x4 acc = (f32x4){0.f, 0.f, 0.f, 0.f};
    acc = MFMA_B16(pa0, cb0, acc);
    acc = MFMA_B16(pa1, cb1, acc);
    f32x4 o;
    #pragma unroll
    for (int e = 0; e < 4; ++e) o[e] = (hcur[e] - acc[e]) * sc;
    if (fs) o = hcur;
    *(f32x4*)(op + (size_t)ft * 16) = o;
  }
}

extern "C" void kernel_launch(void* const* d_in, const int* in_sizes, int n_in,
                              void* d_out, int out_size, void* d_ws, size_t ws_size,
                              hipStream_t stream) {
  const float* H = (const float*)d_in[0];   // 8*4096*1024 fp32
  const float* P = (const float*)d_in[1];   // 1024*64 fp32
  float* out = (float*)d_out;
  // ws: partial f32[65536] | Ptf u16[65536] | Pbf u16[65536] | Wf u16[4096]
  //     | Sc f32[32768] | Cf u16[2097152]   (~4.9 MB total)
  float* partial = (float*)d_ws;
  unsigned short* Ptf = (unsigned short*)(partial + 16 * 4096);
  unsigned short* Pbf = Ptf + 65536;
  unsigned short* Wf = Pbf + 65536;
  float* Sc = (float*)(Wf + 4096);
  unsigned short* Cf = (unsigned short*)(Sc + 32768);

  pp_gram<<<16, 256, 0, stream>>>(P, partial, Ptf, Pbf);
  pp_invert<<<1, 256, 0, stream>>>(partial, Wf);
  pp_y<<<512, 256, 0, stream>>>(H, Ptf, Wf, Cf, Sc);
  pp_apply<<<512, 256, 0, stream>>>(H, Pbf, Cf, Sc, out);
}